// Round 11
// baseline (493.086 us; speedup 1.0000x reference)
//
#include <hip/hip_runtime.h>
#include <hip/hip_bf16.h>

#define HID 128
#define NNODES 50000
#define NEDGES 800000
#define NGRAPHS 64
#define BN_EPS 1e-5f
#define CAP 64  // bucket capacity = wave size; deg ~ Poisson(16), P(>63) ~ 1e-21

typedef __attribute__((ext_vector_type(8))) short short8;   // 8 bf16 (4 VGPRs)
typedef __attribute__((ext_vector_type(4))) float f32x4;    // MFMA acc

static __device__ __forceinline__ unsigned short f2bf(float v) {
  __hip_bfloat16 b = __float2bfloat16(v);  // round-to-nearest
  return *reinterpret_cast<unsigned short*>(&b);
}
static __device__ __forceinline__ float bf2f(unsigned short u) {
  return __uint_as_float(((unsigned)u) << 16);
}

// split fp32 -> hi+lo bf16 pair (bf16x3 scheme), 8 contiguous LDS floats
static __device__ __forceinline__ void split8(const float* __restrict__ p,
                                              short8& hi, short8& lo) {
  #pragma unroll
  for (int j = 0; j < 8; j++) {
    float v = p[j];
    unsigned short h = f2bf(v);
    hi[j] = (short)h;
    lo[j] = (short)f2bf(v - bf2f(h));
  }
}

// ===========================================================================
// prep: xbf = bf16(node_emb[x_idx]) + weight pack (MFMA B-frag, hi/lo split)
// Wpk: hi at idx, lo at idx+65536; idx=(((m*8+t)*4+q)*64+l)*8+j,
// lane l holds W[k=(l>>4)*8+j+q*32][n=t*16+(l&15)], m=layer*2+{0:W1,1:W2}
// ===========================================================================
__global__ __launch_bounds__(256) void prep_kernel(
    const int* __restrict__ x_idx, const float* __restrict__ node_emb,
    uint2* __restrict__ xb4, const float* __restrict__ W1,
    const float* __restrict__ W2, unsigned short* __restrict__ Wpk) {
  int i = blockIdx.x * 256 + threadIdx.x;
  int stride = gridDim.x * 256;
  const float4* ne4 = (const float4*)node_emb;
  for (int t = i; t < NNODES * (HID / 4); t += stride) {
    int n = t >> 5;  // 32 float4 per row
    int c4 = t & 31;
    float4 v = ne4[x_idx[n] * 32 + c4];
    uint2 o;
    o.x = (unsigned)f2bf(v.x) | ((unsigned)f2bf(v.y) << 16);
    o.y = (unsigned)f2bf(v.z) | ((unsigned)f2bf(v.w) << 16);
    xb4[t] = o;
  }
  for (int idx = i; idx < 65536; idx += stride) {
    int j = idx & 7;
    int l = (idx >> 3) & 63;
    int q = (idx >> 9) & 3;
    int t = (idx >> 11) & 7;
    int m = idx >> 14;
    int k = ((l >> 4) << 3) + j + (q << 5);
    int n = (t << 4) + (l & 15);
    int layer = m >> 1;
    const float* W = (m & 1) ? W2 : W1;
    float w = W[(size_t)layer * HID * HID + k * HID + n];
    unsigned short h = f2bf(w);
    Wpk[idx] = h;
    Wpk[idx + 65536] = f2bf(w - bf2f(h));
  }
}

// ===========================================================================
// csr: bucket scatter. pos = atomicAdd(cnt[dst]); eout[dst*64+pos] = packed.
// ===========================================================================
__global__ __launch_bounds__(256) void csr_kernel(
    const int* __restrict__ eidx, const int* __restrict__ eattr,
    int* __restrict__ cnt, int* __restrict__ eout) {
  int e = blockIdx.x * 256 + threadIdx.x;
  if (e >= NEDGES) return;
  int d = eidx[NEDGES + e];
  int pos = atomicAdd(&cnt[d], 1);
  if (pos < CAP) eout[((size_t)d << 6) + pos] = eidx[e] | (eattr[e] << 16);
}

// ===========================================================================
// Fused GINE layer. 256 threads (4 waves), NT=16 nodes (50000/16 = 3125
// blocks exactly -> no bounds checks).
// Gather: wave owns 4 nodes; its whole edge bucket is loaded in ONE
// coalesced wave-load into registers (ew), edge words then come from __shfl
// (1-hop chains). Lanes = 16 ch-octets x 4 edge slots, 16B/lane bf16 rows.
// GEMM: wave w -> ch tiles 2w, 2w+1 via mfma_f32_16x16x32_bf16, bf16x3
// hi/lo split (fp32-grade).
// ===========================================================================
#define NT 16
#define LDAF 132  // 128+4 floats: float4-aligned rows
#define GRID_GINE (NNODES / NT)  // 3125 exact

__global__ __launch_bounds__(256, 6) void gine_mlp_kernel(
    const unsigned short* __restrict__ in_bf,
    const float* __restrict__ instats,
    const float* __restrict__ gam, const float* __restrict__ bet,
    const int* __restrict__ cnt, const int* __restrict__ eout,
    const float* __restrict__ edge_emb,
    const short8* __restrict__ Wh, const short8* __restrict__ Wl,
    const float* __restrict__ b1, const float* __restrict__ b2,
    unsigned short* __restrict__ out_bf, float* __restrict__ stats,
    const int* __restrict__ batch, float* __restrict__ gpool) {
  __shared__ __align__(16) float hA[NT * LDAF];  // h0 -> h1 -> h2 (reused)
  __shared__ __align__(16) float sheL[4 * HID];  // sh[c] + edge_emb[a][c]

  const int tid = threadIdx.x;
  const int lane = tid & 63;
  const int wave = tid >> 6;   // 0..3
  const int base = blockIdx.x * NT;

  // ---- fill she table (BN shift of previous layer folded into edge emb) ----
  for (int t = tid; t < 4 * HID; t += 256) {
    int c = t & 127;
    float shc = 0.0f;
    if (instats) {
      float mu = instats[c] * (1.0f / NNODES);
      float var = instats[HID + c] * (1.0f / NNODES) - mu * mu;
      float s = gam[c] * rsqrtf(var + BN_EPS);
      shc = bet[c] - mu * s;
    }
    sheL[t] = shc + edge_emb[t];
  }

  // ---- per-lane affine over 8 channels (c8*8 .. c8*8+7) ----
  const int c8 = lane & 15;
  const int grp = lane >> 4;
  float scl8[8], sh8[8];
  #pragma unroll
  for (int j = 0; j < 8; j++) { scl8[j] = 1.0f; sh8[j] = 0.0f; }
  if (instats) {
    #pragma unroll
    for (int j = 0; j < 8; j++) {
      int c = c8 * 8 + j;
      float mu = instats[c] * (1.0f / NNODES);
      float var = instats[HID + c] * (1.0f / NNODES) - mu * mu;
      float s = gam[c] * rsqrtf(var + BN_EPS);
      scl8[j] = s;
      sh8[j] = bet[c] - mu * s;
    }
  }
  __syncthreads();  // sheL ready

  // ---- phase 1: gather ----
  {
    const short8* in8 = (const short8*)in_bf;  // row = 16 short8s
    const int node0 = base + wave * 4;
    int ew[4], degs[4];
    short8 selfr[4];
    #pragma unroll
    for (int i = 0; i < 4; i++) {  // 12 loads in flight immediately
      int nd = node0 + i;
      degs[i] = min(cnt[nd], CAP);
      ew[i] = eout[((size_t)nd << 6) + lane];  // whole bucket, coalesced
      selfr[i] = in8[nd * 16 + c8];
    }
    #pragma unroll
    for (int i = 0; i < 4; i++) {
      float acc[8];
      if (grp == 0) {
        #pragma unroll
        for (int j = 0; j < 8; j++)
          acc[j] = fmaf(bf2f((unsigned short)selfr[i][j]), scl8[j], sh8[j]);
      } else {
        #pragma unroll
        for (int j = 0; j < 8; j++) acc[j] = 0.0f;
      }
      int deg = degs[i];
      for (int e = 0; e < deg; e += 8) {  // 8 edges: 2 per slot, 1-hop loads
        int p0 = __shfl(ew[i], e + grp);
        int p1 = __shfl(ew[i], e + 4 + grp);
        bool v0 = (e + grp) < deg;
        bool v1 = (e + 4 + grp) < deg;
        short8 x0 = in8[(p0 & 0xFFFF) * 16 + c8];
        short8 x1 = in8[(p1 & 0xFFFF) * 16 + c8];
        const float4* sp0 = (const float4*)&sheL[((p0 >> 16) & 3) * HID + c8 * 8];
        const float4* sp1 = (const float4*)&sheL[((p1 >> 16) & 3) * HID + c8 * 8];
        float4 sA0 = sp0[0], sA1 = sp0[1];
        float4 sB0 = sp1[0], sB1 = sp1[1];
        #pragma unroll
        for (int j = 0; j < 8; j++) {
          float se0 = (j < 4) ? ((const float*)&sA0)[j] : ((const float*)&sA1)[j - 4];
          float se1 = (j < 4) ? ((const float*)&sB0)[j] : ((const float*)&sB1)[j - 4];
          float t0 = fmaxf(fmaf(bf2f((unsigned short)x0[j]), scl8[j], se0), 0.0f);
          float t1 = fmaxf(fmaf(bf2f((unsigned short)x1[j]), scl8[j], se1), 0.0f);
          acc[j] += (v0 ? t0 : 0.0f) + (v1 ? t1 : 0.0f);
        }
      }
      // combine the 4 edge-slot partials (same channels across slots)
      #pragma unroll
      for (int j = 0; j < 8; j++) {
        acc[j] += __shfl_xor(acc[j], 16);
        acc[j] += __shfl_xor(acc[j], 32);
      }
      if (grp == 0) {
        int nrow = wave * 4 + i;
        float4 lo = make_float4(acc[0], acc[1], acc[2], acc[3]);
        float4 hi = make_float4(acc[4], acc[5], acc[6], acc[7]);
        *(float4*)&hA[nrow * LDAF + c8 * 8] = lo;
        *(float4*)&hA[nrow * LDAF + c8 * 8 + 4] = hi;
      }
    }
  }
  __syncthreads();

  const int col = lane & 15;
  const int quad = lane >> 4;
  const int rbase = quad * 4;
  const int ch0 = wave * 32 + col;  // wave handles ch tiles 2w, 2w+1
  const int ch1 = ch0 + 16;
  const int aoff = quad * 8;

  // ---- phase 2: GEMM1 (hA @ W1 + b1, relu) -> back into hA ----
  {
    f32x4 a00 = {0.f, 0.f, 0.f, 0.f}, a01 = a00;
    #pragma unroll
    for (int q = 0; q < 4; q++) {
      int f0 = (wave * 2 + 0) * 256 + q * 64 + lane;
      int f1 = (wave * 2 + 1) * 256 + q * 64 + lane;
      short8 b0h = Wh[f0], b0l = Wl[f0];
      short8 b1h = Wh[f1], b1l = Wl[f1];
      short8 ah, al;
      split8(&hA[col * LDAF + q * 32 + aoff], ah, al);
      a00 = __builtin_amdgcn_mfma_f32_16x16x32_bf16(ah, b0h, a00, 0, 0, 0);
      a00 = __builtin_amdgcn_mfma_f32_16x16x32_bf16(al, b0h, a00, 0, 0, 0);
      a00 = __builtin_amdgcn_mfma_f32_16x16x32_bf16(ah, b0l, a00, 0, 0, 0);
      a01 = __builtin_amdgcn_mfma_f32_16x16x32_bf16(ah, b1h, a01, 0, 0, 0);
      a01 = __builtin_amdgcn_mfma_f32_16x16x32_bf16(al, b1h, a01, 0, 0, 0);
      a01 = __builtin_amdgcn_mfma_f32_16x16x32_bf16(ah, b1l, a01, 0, 0, 0);
    }
    __syncthreads();  // all GEMM1 reads of hA complete
    float bb0 = b1[ch0], bb1 = b1[ch1];
    #pragma unroll
    for (int r = 0; r < 4; r++) {
      hA[(rbase + r) * LDAF + ch0] = fmaxf(a00[r] + bb0, 0.0f);
      hA[(rbase + r) * LDAF + ch1] = fmaxf(a01[r] + bb1, 0.0f);
    }
  }
  __syncthreads();

  // ---- phase 3: GEMM2 (h1 @ W2 + b2, relu) -> back into hA ----
  {
    f32x4 a00 = {0.f, 0.f, 0.f, 0.f}, a01 = a00;
    #pragma unroll
    for (int q = 0; q < 4; q++) {
      int f0 = 2048 + (wave * 2 + 0) * 256 + q * 64 + lane;
      int f1 = 2048 + (wave * 2 + 1) * 256 + q * 64 + lane;
      short8 b0h = Wh[f0], b0l = Wl[f0];
      short8 b1h = Wh[f1], b1l = Wl[f1];
      short8 ah, al;
      split8(&hA[col * LDAF + q * 32 + aoff], ah, al);
      a00 = __builtin_amdgcn_mfma_f32_16x16x32_bf16(ah, b0h, a00, 0, 0, 0);
      a00 = __builtin_amdgcn_mfma_f32_16x16x32_bf16(al, b0h, a00, 0, 0, 0);
      a00 = __builtin_amdgcn_mfma_f32_16x16x32_bf16(ah, b0l, a00, 0, 0, 0);
      a01 = __builtin_amdgcn_mfma_f32_16x16x32_bf16(ah, b1h, a01, 0, 0, 0);
      a01 = __builtin_amdgcn_mfma_f32_16x16x32_bf16(al, b1h, a01, 0, 0, 0);
      a01 = __builtin_amdgcn_mfma_f32_16x16x32_bf16(ah, b1l, a01, 0, 0, 0);
    }
    __syncthreads();  // all GEMM2 reads complete
    float bb0 = b2[ch0], bb1 = b2[ch1];
    #pragma unroll
    for (int r = 0; r < 4; r++) {
      hA[(rbase + r) * LDAF + ch0] = fmaxf(a00[r] + bb0, 0.0f);
      hA[(rbase + r) * LDAF + ch1] = fmaxf(a01[r] + bb1, 0.0f);
    }
  }
  __syncthreads();

  // ---- phase 4: epilogue (h2 in hA) ----
  {
    const int c = tid & 127;
    const int yy = tid >> 7;  // 0/1 -> nodes [yy*8, yy*8+8)
    float lsum = 0.0f, lsq = 0.0f;
    if (out_bf) {
      #pragma unroll
      for (int i = 0; i < 8; i++) {
        int n = yy * 8 + i;
        float v = hA[n * LDAF + c];
        out_bf[(base + n) * HID + c] = f2bf(v);
        lsum += v;
        lsq += v * v;
      }
    } else {
      int curg = -1;
      float pacc = 0.0f;
      for (int i = 0; i < 8; i++) {
        int n = yy * 8 + i;
        float v = hA[n * LDAF + c];
        lsum += v;
        lsq += v * v;
        int bg = batch[base + n];
        if (bg != curg) {
          if (curg >= 0) unsafeAtomicAdd(&gpool[curg * HID + c], pacc);
          curg = bg;
          pacc = 0.0f;
        }
        pacc += v;
      }
      if (curg >= 0) unsafeAtomicAdd(&gpool[curg * HID + c], pacc);
    }
    unsafeAtomicAdd(&stats[c], lsum);
    unsafeAtomicAdd(&stats[HID + c], lsq);
  }
}

// ---------------------------------------------------------------------------
// out[g,c] = scl_c * gpool[g,c] + cnt_g * sh_c  (BN affine commutes with pool)
__device__ __forceinline__ int lbound(const int* __restrict__ arr, int n,
                                      int key) {
  int lo = 0, hi = n;
  while (lo < hi) {
    int mid = (lo + hi) >> 1;
    if (arr[mid] < key) lo = mid + 1; else hi = mid;
  }
  return lo;
}

__global__ __launch_bounds__(128) void finish_kernel(
    const float* __restrict__ gpool, const float* __restrict__ stats,
    const float* __restrict__ gam, const float* __restrict__ bet,
    const int* __restrict__ batch, float* __restrict__ out) {
  __shared__ int cnt_s;
  int g = blockIdx.x, c = threadIdx.x;
  if (c == 0)
    cnt_s = lbound(batch, NNODES, g + 1) - lbound(batch, NNODES, g);
  __syncthreads();
  float mu = stats[c] * (1.0f / NNODES);
  float var = stats[HID + c] * (1.0f / NNODES) - mu * mu;
  float scl = gam[c] * rsqrtf(var + BN_EPS);
  float sh = bet[c] - mu * scl;
  out[g * HID + c] = fmaf(gpool[g * HID + c], scl, (float)cnt_s * sh);
}

// ---------------------------------------------------------------------------
extern "C" void kernel_launch(void* const* d_in, const int* in_sizes, int n_in,
                              void* d_out, int out_size, void* d_ws, size_t ws_size,
                              hipStream_t stream) {
  const int* x_idx = (const int*)d_in[0];
  const int* eidx = (const int*)d_in[1];   // [2, E]: src row then dst row
  const int* eattr = (const int*)d_in[2];
  const int* batch = (const int*)d_in[3];
  const float* node_emb = (const float*)d_in[4];
  const float* edge_emb = (const float*)d_in[5];
  const float* W1 = (const float*)d_in[6];
  const float* b1 = (const float*)d_in[7];
  const float* W2 = (const float*)d_in[8];
  const float* b2 = (const float*)d_in[9];
  const float* bn_g = (const float*)d_in[10];
  const float* bn_b = (const float*)d_in[11];
  float* out = (float*)d_out;

  const size_t nfeat = (size_t)NNODES * HID;
  unsigned short* xbf = (unsigned short*)d_ws;  // [N,H] bf16
  unsigned short* h2bf = xbf + nfeat;           // [N,H] bf16
  float* stats0 = (float*)(h2bf + nfeat);       // [2,H]
  float* stats1 = stats0 + 2 * HID;             // [2,H]
  float* gpool = stats1 + 2 * HID;              // [G,H]
  int* cnt = (int*)(gpool + NGRAPHS * HID);     // [N]   (zeroed with stats)
  int* eout = cnt + NNODES;                     // [N*CAP]
  unsigned short* Wpk = (unsigned short*)(eout + (size_t)NNODES * CAP);
  size_t needed = (size_t)((char*)(Wpk + 131072) - (char*)d_ws);
  if (ws_size < needed) return;  // fails validation loudly, doesn't corrupt

  // zero stats0, stats1, gpool, cnt in one shot (contiguous)
  hipMemsetAsync(stats0, 0, (4 * HID + NGRAPHS * HID + NNODES) * sizeof(int),
                 stream);

  prep_kernel<<<1024, 256, 0, stream>>>(x_idx, node_emb, (uint2*)xbf, W1, W2,
                                        Wpk);
  csr_kernel<<<(NEDGES + 255) / 256, 256, 0, stream>>>(eidx, eattr, cnt, eout);

  const short8* Wfh = (const short8*)Wpk;  // 8192 frags (hi)
  const short8* Wfl = Wfh + 8192;          // 8192 frags (lo)
  // layer 0: in = xbf (identity affine), out -> h2bf, stats0
  gine_mlp_kernel<<<GRID_GINE, 256, 0, stream>>>(
      xbf, nullptr, nullptr, nullptr, cnt, eout, edge_emb,
      Wfh + 0 * 2048, Wfl + 0 * 2048, b1, b2, h2bf, stats0, nullptr, nullptr);
  // layer 1: in = h2bf with BN(layer0) folded, out -> gpool + stats1
  gine_mlp_kernel<<<GRID_GINE, 256, 0, stream>>>(
      h2bf, stats0, bn_g, bn_b, cnt, eout, edge_emb,
      Wfh + 2 * 2048, Wfl + 2 * 2048, b1 + HID, b2 + HID, nullptr, stats1,
      batch, gpool);
  // final: out = scl*gpool + cnt*sh
  finish_kernel<<<NGRAPHS, 128, 0, stream>>>(gpool, stats1, bn_g + HID,
                                             bn_b + HID, batch, out);
}

// Round 12
// 482.832 us; speedup vs baseline: 1.0212x; 1.0212x over previous
//
#include <hip/hip_runtime.h>
#include <hip/hip_bf16.h>

#define HID 128
#define NNODES 50000
#define NEDGES 800000
#define NGRAPHS 64
#define BN_EPS 1e-5f
#define CAP 64  // bucket capacity; deg ~ Poisson(16), P(deg>63) ~ 1e-21

typedef __attribute__((ext_vector_type(8))) short short8;   // 8 bf16 (4 VGPRs)
typedef __attribute__((ext_vector_type(4))) float f32x4;    // MFMA acc

static __device__ __forceinline__ unsigned short f2bf(float v) {
  __hip_bfloat16 b = __float2bfloat16(v);  // round-to-nearest
  return *reinterpret_cast<unsigned short*>(&b);
}
static __device__ __forceinline__ float bf2f(unsigned short u) {
  return __uint_as_float(((unsigned)u) << 16);
}

// split fp32 -> hi+lo bf16 pair (bf16x3 scheme), 8 contiguous LDS floats
static __device__ __forceinline__ void split8(const float* __restrict__ p,
                                              short8& hi, short8& lo) {
  #pragma unroll
  for (int j = 0; j < 8; j++) {
    float v = p[j];
    unsigned short h = f2bf(v);
    hi[j] = (short)h;
    lo[j] = (short)f2bf(v - bf2f(h));
  }
}

// ===========================================================================
// prep (single kernel): xbf = bf16(node_emb[x_idx]) + bucket-CSR build +
// weight pack (MFMA B-frag layout, hi/lo split).  [round-10 proven]
// ===========================================================================
__global__ __launch_bounds__(256) void prep_kernel(
    const int* __restrict__ x_idx, const float* __restrict__ node_emb,
    unsigned int* __restrict__ xb2, const int* __restrict__ eidx,
    const int* __restrict__ eattr, int* __restrict__ cnt,
    int* __restrict__ eout, const float* __restrict__ W1,
    const float* __restrict__ W2, unsigned short* __restrict__ Wpk) {
  int i = blockIdx.x * 256 + threadIdx.x;
  int stride = gridDim.x * 256;
  const float2* ne2 = (const float2*)node_emb;
  for (int t = i; t < NNODES * (HID / 2); t += stride) {
    int n = t >> 6;  // HID/2 == 64
    int c2 = t & 63;
    float2 v = ne2[x_idx[n] * 64 + c2];
    xb2[t] = (unsigned)f2bf(v.x) | ((unsigned)f2bf(v.y) << 16);
  }
  for (int e = i; e < NEDGES; e += stride) {
    int d = eidx[NEDGES + e];
    int pos = atomicAdd(&cnt[d], 1);
    if (pos < CAP) eout[((size_t)d << 6) + pos] = eidx[e] | (eattr[e] << 16);
  }
  for (int idx = i; idx < 65536; idx += stride) {
    int j = idx & 7;
    int l = (idx >> 3) & 63;
    int q = (idx >> 9) & 3;
    int t = (idx >> 11) & 7;
    int m = idx >> 14;
    int k = ((l >> 4) << 3) + j + (q << 5);
    int n = (t << 4) + (l & 15);
    int layer = m >> 1;
    const float* W = (m & 1) ? W2 : W1;
    float w = W[(size_t)layer * HID * HID + k * HID + n];
    unsigned short h = f2bf(w);
    Wpk[idx] = h;
    Wpk[idx + 65536] = f2bf(w - bf2f(h));
  }
}

// ===========================================================================
// Fused GINE layer [round-10 structure] + persistent-block work stealing.
// Grid = 1024 blocks (4/CU, 32 waves/CU = HW cap); each block pulls node
// tiles (NT=32) from a global counter until exhausted.
// Gather: wave w owns nodes [w*4, w*4+4); lanes = 16 ch-octets x 4 edge
// slots; one wave load = 4 edge rows (bf16, 16B/lane); eout loads issue
// independently (addresses static within bucket).
// GEMM: wave w -> ch-tile w (16 ch) x 2 row-tiles, mfma 16x16x32_bf16,
// bf16x3 hi/lo split (fp32-grade).
// ===========================================================================
#define NT 32
#define LDAF 132  // 128+4 floats: float4-aligned rows
#define NTILES ((NNODES + NT - 1) / NT)  // 1563
#define GRID_GINE 1024

__global__ __launch_bounds__(512, 8) void gine_mlp_kernel(
    const unsigned short* __restrict__ in_bf,
    const float* __restrict__ instats,
    const float* __restrict__ gam, const float* __restrict__ bet,
    const int* __restrict__ cnt, const int* __restrict__ eout,
    const float* __restrict__ edge_emb,
    const short8* __restrict__ Wh, const short8* __restrict__ Wl,
    const float* __restrict__ b1, const float* __restrict__ b2,
    unsigned short* __restrict__ out_bf, float* __restrict__ stats,
    const int* __restrict__ batch, float* __restrict__ gpool,
    int* __restrict__ tile_ctr) {
  __shared__ __align__(16) float hA[NT * LDAF];  // h0 -> h1 -> h2 (reused)
  __shared__ __align__(16) float sheL[4 * HID];  // sh[c] + edge_emb[a][c]
  __shared__ int tile_s;

  const int tid = threadIdx.x;
  const int lane = tid & 63;
  const int wave = tid >> 6;   // 0..7

  // ---- per-block setup (amortized over stolen tiles) ----
  if (tid < 4 * HID) {
    int c = tid & 127;
    float shc = 0.0f;
    if (instats) {
      float mu = instats[c] * (1.0f / NNODES);
      float var = instats[HID + c] * (1.0f / NNODES) - mu * mu;
      float s = gam[c] * rsqrtf(var + BN_EPS);
      shc = bet[c] - mu * s;
    }
    sheL[tid] = shc + edge_emb[tid];
  }

  const int c8 = lane & 15;
  const int grp = lane >> 4;
  float scl8[8], sh8[8];
  #pragma unroll
  for (int j = 0; j < 8; j++) { scl8[j] = 1.0f; sh8[j] = 0.0f; }
  if (instats) {
    #pragma unroll
    for (int j = 0; j < 8; j++) {
      int c = c8 * 8 + j;
      float mu = instats[c] * (1.0f / NNODES);
      float var = instats[HID + c] * (1.0f / NNODES) - mu * mu;
      float s = gam[c] * rsqrtf(var + BN_EPS);
      scl8[j] = s;
      sh8[j] = bet[c] - mu * s;
    }
  }

  const int col = lane & 15;
  const int quad = lane >> 4;
  const int rbase = quad * 4;
  const int ch0 = wave * 16 + col;  // this wave's 16-channel tile
  const int aoff = quad * 8;
  const float bb1 = b1[ch0];
  const float bb2 = b2[ch0];

  for (;;) {
    if (tid == 0) tile_s = atomicAdd(tile_ctr, 1);
    __syncthreads();  // publishes tile_s; also: prev epilogue hA reads done
    const int tile = tile_s;
    if (tile >= NTILES) break;
    const int base = tile * NT;

    // ---- phase 1: gather ----
    {
      const short8* in8 = (const short8*)in_bf;  // row = 16 short8s
      int node0 = base + wave * 4;
      int degs[4];
      #pragma unroll
      for (int i = 0; i < 4; i++) {
        int nd = node0 + i;
        degs[i] = (nd < NNODES) ? min(cnt[nd], CAP) : 0;
      }
      for (int i = 0; i < 4; i++) {
        int node = node0 + i;
        int nrow = wave * 4 + i;
        float acc[8];
        #pragma unroll
        for (int j = 0; j < 8; j++) acc[j] = 0.0f;
        if (node < NNODES) {
          int deg = degs[i];
          const int* ep = eout + ((size_t)node << 6);
          if (grp == 0) {
            short8 s = in8[node * 16 + c8];
            #pragma unroll
            for (int j = 0; j < 8; j++)
              acc[j] = fmaf(bf2f((unsigned short)s[j]), scl8[j], sh8[j]);
          }
          int e = 0;
          for (; e + 8 <= deg; e += 8) {  // 8 edges: 2 per slot
            int pA = ep[e + grp];
            int pB = ep[e + 4 + grp];
            short8 xA = in8[(pA & 0xFFFF) * 16 + c8];
            short8 xB = in8[(pB & 0xFFFF) * 16 + c8];
            const float4* sA = (const float4*)&sheL[((pA >> 16) << 7) + c8 * 8];
            const float4* sB = (const float4*)&sheL[((pB >> 16) << 7) + c8 * 8];
            float4 sA0 = sA[0], sA1 = sA[1], sB0 = sB[0], sB1 = sB[1];
            #pragma unroll
            for (int j = 0; j < 8; j++) {
              float seA = (j < 4) ? ((const float*)&sA0)[j] : ((const float*)&sA1)[j - 4];
              float seB = (j < 4) ? ((const float*)&sB0)[j] : ((const float*)&sB1)[j - 4];
              acc[j] += fmaxf(fmaf(bf2f((unsigned short)xA[j]), scl8[j], seA), 0.0f) +
                        fmaxf(fmaf(bf2f((unsigned short)xB[j]), scl8[j], seB), 0.0f);
            }
          }
          if (e + 4 <= deg) {
            int pA = ep[e + grp];
            short8 xA = in8[(pA & 0xFFFF) * 16 + c8];
            const float4* sA = (const float4*)&sheL[((pA >> 16) << 7) + c8 * 8];
            float4 sA0 = sA[0], sA1 = sA[1];
            #pragma unroll
            for (int j = 0; j < 8; j++) {
              float seA = (j < 4) ? ((const float*)&sA0)[j] : ((const float*)&sA1)[j - 4];
              acc[j] += fmaxf(fmaf(bf2f((unsigned short)xA[j]), scl8[j], seA), 0.0f);
            }
            e += 4;
          }
          int rem = deg - e;  // 0..3
          if (grp < rem) {
            int pA = ep[e + grp];
            short8 xA = in8[(pA & 0xFFFF) * 16 + c8];
            const float4* sA = (const float4*)&sheL[((pA >> 16) << 7) + c8 * 8];
            float4 sA0 = sA[0], sA1 = sA[1];
            #pragma unroll
            for (int j = 0; j < 8; j++) {
              float seA = (j < 4) ? ((const float*)&sA0)[j] : ((const float*)&sA1)[j - 4];
              acc[j] += fmaxf(fmaf(bf2f((unsigned short)xA[j]), scl8[j], seA), 0.0f);
            }
          }
        }
        #pragma unroll
        for (int j = 0; j < 8; j++) {
          acc[j] += __shfl_xor(acc[j], 16);
          acc[j] += __shfl_xor(acc[j], 32);
        }
        if (grp == 0) {
          float4 lo = make_float4(acc[0], acc[1], acc[2], acc[3]);
          float4 hi = make_float4(acc[4], acc[5], acc[6], acc[7]);
          *(float4*)&hA[nrow * LDAF + c8 * 8] = lo;
          *(float4*)&hA[nrow * LDAF + c8 * 8 + 4] = hi;
        }
      }
    }
    __syncthreads();

    // ---- phase 2: GEMM1 (hA @ W1 + b1, relu) -> back into hA ----
    {
      f32x4 a0 = {0.f, 0.f, 0.f, 0.f}, a1 = a0;
      #pragma unroll
      for (int q = 0; q < 4; q++) {
        int f0 = wave * 256 + q * 64 + lane;
        short8 b0h = Wh[f0], b0l = Wl[f0];
        short8 a0h, a0l, a1h, a1l;
        split8(&hA[col * LDAF + q * 32 + aoff], a0h, a0l);
        split8(&hA[(16 + col) * LDAF + q * 32 + aoff], a1h, a1l);
        a0 = __builtin_amdgcn_mfma_f32_16x16x32_bf16(a0h, b0h, a0, 0, 0, 0);
        a0 = __builtin_amdgcn_mfma_f32_16x16x32_bf16(a0l, b0h, a0, 0, 0, 0);
        a0 = __builtin_amdgcn_mfma_f32_16x16x32_bf16(a0h, b0l, a0, 0, 0, 0);
        a1 = __builtin_amdgcn_mfma_f32_16x16x32_bf16(a1h, b0h, a1, 0, 0, 0);
        a1 = __builtin_amdgcn_mfma_f32_16x16x32_bf16(a1l, b0h, a1, 0, 0, 0);
        a1 = __builtin_amdgcn_mfma_f32_16x16x32_bf16(a1h, b0l, a1, 0, 0, 0);
      }
      __syncthreads();  // all GEMM1 reads of hA complete
      #pragma unroll
      for (int r = 0; r < 4; r++) {
        hA[(rbase + r) * LDAF + ch0] = fmaxf(a0[r] + bb1, 0.0f);
        hA[(16 + rbase + r) * LDAF + ch0] = fmaxf(a1[r] + bb1, 0.0f);
      }
    }
    __syncthreads();

    // ---- phase 3: GEMM2 (h1 @ W2 + b2, relu) -> back into hA ----
    {
      f32x4 a0 = {0.f, 0.f, 0.f, 0.f}, a1 = a0;
      #pragma unroll
      for (int q = 0; q < 4; q++) {
        int f0 = 2048 + wave * 256 + q * 64 + lane;  // gemm2 frags
        short8 b0h = Wh[f0], b0l = Wl[f0];
        short8 a0h, a0l, a1h, a1l;
        split8(&hA[col * LDAF + q * 32 + aoff], a0h, a0l);
        split8(&hA[(16 + col) * LDAF + q * 32 + aoff], a1h, a1l);
        a0 = __builtin_amdgcn_mfma_f32_16x16x32_bf16(a0h, b0h, a0, 0, 0, 0);
        a0 = __builtin_amdgcn_mfma_f32_16x16x32_bf16(a0l, b0h, a0, 0, 0, 0);
        a0 = __builtin_amdgcn_mfma_f32_16x16x32_bf16(a0h, b0l, a0, 0, 0, 0);
        a1 = __builtin_amdgcn_mfma_f32_16x16x32_bf16(a1h, b0h, a1, 0, 0, 0);
        a1 = __builtin_amdgcn_mfma_f32_16x16x32_bf16(a1l, b0h, a1, 0, 0, 0);
        a1 = __builtin_amdgcn_mfma_f32_16x16x32_bf16(a1h, b0l, a1, 0, 0, 0);
      }
      __syncthreads();  // all GEMM2 reads complete
      #pragma unroll
      for (int r = 0; r < 4; r++) {
        hA[(rbase + r) * LDAF + ch0] = fmaxf(a0[r] + bb2, 0.0f);
        hA[(16 + rbase + r) * LDAF + ch0] = fmaxf(a1[r] + bb2, 0.0f);
      }
    }
    __syncthreads();

    // ---- phase 4: epilogue (h2 in hA); first 256 threads only ----
    if (tid < 256) {
      const int c = tid & 127;
      const int yy = tid >> 7;
      float lsum = 0.0f, lsq = 0.0f;
      if (out_bf) {
        #pragma unroll 4
        for (int i = 0; i < 16; i++) {
          int n = yy * 16 + i;
          int node = base + n;
          if (node < NNODES) {
            float v = hA[n * LDAF + c];
            out_bf[node * HID + c] = f2bf(v);
            lsum += v;
            lsq += v * v;
          }
        }
      } else {
        int curg = -1;
        float pacc = 0.0f;
        for (int i = 0; i < 16; i++) {
          int n = yy * 16 + i;
          int node = base + n;
          if (node < NNODES) {
            float v = hA[n * LDAF + c];
            lsum += v;
            lsq += v * v;
            int bg = batch[node];
            if (bg != curg) {
              if (curg >= 0) unsafeAtomicAdd(&gpool[curg * HID + c], pacc);
              curg = bg;
              pacc = 0.0f;
            }
            pacc += v;
          }
        }
        if (curg >= 0) unsafeAtomicAdd(&gpool[curg * HID + c], pacc);
      }
      unsafeAtomicAdd(&stats[c], lsum);
      unsafeAtomicAdd(&stats[HID + c], lsq);
    }
    // loop-top barrier protects hA against next tile's gather
  }
}

// ---------------------------------------------------------------------------
// out[g,c] = scl_c * gpool[g,c] + cnt_g * sh_c  (BN affine commutes with pool)
__device__ __forceinline__ int lbound(const int* __restrict__ arr, int n,
                                      int key) {
  int lo = 0, hi = n;
  while (lo < hi) {
    int mid = (lo + hi) >> 1;
    if (arr[mid] < key) lo = mid + 1; else hi = mid;
  }
  return lo;
}

__global__ __launch_bounds__(128) void finish_kernel(
    const float* __restrict__ gpool, const float* __restrict__ stats,
    const float* __restrict__ gam, const float* __restrict__ bet,
    const int* __restrict__ batch, float* __restrict__ out) {
  __shared__ int cnt_s;
  int g = blockIdx.x, c = threadIdx.x;
  if (c == 0)
    cnt_s = lbound(batch, NNODES, g + 1) - lbound(batch, NNODES, g);
  __syncthreads();
  float mu = stats[c] * (1.0f / NNODES);
  float var = stats[HID + c] * (1.0f / NNODES) - mu * mu;
  float scl = gam[c] * rsqrtf(var + BN_EPS);
  float sh = bet[c] - mu * scl;
  out[g * HID + c] = fmaf(gpool[g * HID + c], scl, (float)cnt_s * sh);
}

// ---------------------------------------------------------------------------
extern "C" void kernel_launch(void* const* d_in, const int* in_sizes, int n_in,
                              void* d_out, int out_size, void* d_ws, size_t ws_size,
                              hipStream_t stream) {
  const int* x_idx = (const int*)d_in[0];
  const int* eidx = (const int*)d_in[1];   // [2, E]: src row then dst row
  const int* eattr = (const int*)d_in[2];
  const int* batch = (const int*)d_in[3];
  const float* node_emb = (const float*)d_in[4];
  const float* edge_emb = (const float*)d_in[5];
  const float* W1 = (const float*)d_in[6];
  const float* b1 = (const float*)d_in[7];
  const float* W2 = (const float*)d_in[8];
  const float* b2 = (const float*)d_in[9];
  const float* bn_g = (const float*)d_in[10];
  const float* bn_b = (const float*)d_in[11];
  float* out = (float*)d_out;

  const size_t nfeat = (size_t)NNODES * HID;
  unsigned short* xbf = (unsigned short*)d_ws;  // [N,H] bf16
  unsigned short* h2bf = xbf + nfeat;           // [N,H] bf16
  float* stats0 = (float*)(h2bf + nfeat);       // [2,H]
  float* stats1 = stats0 + 2 * HID;             // [2,H]
  float* gpool = stats1 + 2 * HID;              // [G,H]
  int* ctrs = (int*)(gpool + NGRAPHS * HID);    // [2] tile counters
  int* cnt = ctrs + 2;                          // [N]  (zeroed with stats)
  int* eout = cnt + NNODES;                     // [N*CAP]
  unsigned short* Wpk = (unsigned short*)(eout + (size_t)NNODES * CAP);
  size_t needed = (size_t)((char*)(Wpk + 131072) - (char*)d_ws);
  if (ws_size < needed) return;  // fails validation loudly, doesn't corrupt

  // zero stats0, stats1, gpool, ctrs, cnt in one shot (contiguous)
  hipMemsetAsync(stats0, 0,
                 (4 * HID + NGRAPHS * HID + 2 + NNODES) * sizeof(int), stream);

  prep_kernel<<<1024, 256, 0, stream>>>(x_idx, node_emb, (unsigned int*)xbf,
                                        eidx, eattr, cnt, eout, W1, W2, Wpk);

  const short8* Wfh = (const short8*)Wpk;  // 8192 frags (hi)
  const short8* Wfl = Wfh + 8192;          // 8192 frags (lo)
  // layer 0: in = xbf (identity affine), out -> h2bf, stats0
  gine_mlp_kernel<<<GRID_GINE, 512, 0, stream>>>(
      xbf, nullptr, nullptr, nullptr, cnt, eout, edge_emb,
      Wfh + 0 * 2048, Wfl + 0 * 2048, b1, b2, h2bf, stats0, nullptr, nullptr,
      ctrs + 0);
  // layer 1: in = h2bf with BN(layer0) folded, out -> gpool + stats1
  gine_mlp_kernel<<<GRID_GINE, 512, 0, stream>>>(
      h2bf, stats0, bn_g, bn_b, cnt, eout, edge_emb,
      Wfh + 2 * 2048, Wfl + 2 * 2048, b1 + HID, b2 + HID, nullptr, stats1,
      batch, gpool, ctrs + 1);
  // final: out = scl*gpool + cnt*sh
  finish_kernel<<<NGRAPHS, 128, 0, stream>>>(gpool, stats1, bn_g + HID,
                                             bn_b + HID, batch, out);
}

// Round 13
// 416.305 us; speedup vs baseline: 1.1844x; 1.1598x over previous
//
#include <hip/hip_runtime.h>
#include <hip/hip_bf16.h>

#define HID 128
#define NNODES 50000
#define NEDGES 800000
#define NGRAPHS 64
#define BN_EPS 1e-5f
#define CAP 64  // bucket capacity; deg ~ Poisson(16), P(deg>63) ~ 1e-21

typedef __attribute__((ext_vector_type(8))) short short8;   // 8 bf16 (4 VGPRs)
typedef __attribute__((ext_vector_type(4))) float f32x4;    // MFMA acc

static __device__ __forceinline__ unsigned short f2bf(float v) {
  __hip_bfloat16 b = __float2bfloat16(v);  // round-to-nearest
  return *reinterpret_cast<unsigned short*>(&b);
}
static __device__ __forceinline__ float bf2f(unsigned short u) {
  return __uint_as_float(((unsigned)u) << 16);
}

// split fp32 -> hi+lo bf16 pair (bf16x3 scheme), 8 contiguous LDS floats
static __device__ __forceinline__ void split8(const float* __restrict__ p,
                                              short8& hi, short8& lo) {
  #pragma unroll
  for (int j = 0; j < 8; j++) {
    float v = p[j];
    unsigned short h = f2bf(v);
    hi[j] = (short)h;
    lo[j] = (short)f2bf(v - bf2f(h));
  }
}

// ===========================================================================
// prep (single kernel): xbf = bf16(node_emb[x_idx]) + bucket-CSR build +
// weight pack (MFMA B-frag layout, hi/lo split).  [round-10 proven]
// ===========================================================================
__global__ __launch_bounds__(256) void prep_kernel(
    const int* __restrict__ x_idx, const float* __restrict__ node_emb,
    unsigned int* __restrict__ xb2, const int* __restrict__ eidx,
    const int* __restrict__ eattr, int* __restrict__ cnt,
    int* __restrict__ eout, const float* __restrict__ W1,
    const float* __restrict__ W2, unsigned short* __restrict__ Wpk) {
  int i = blockIdx.x * 256 + threadIdx.x;
  int stride = gridDim.x * 256;
  const float2* ne2 = (const float2*)node_emb;
  for (int t = i; t < NNODES * (HID / 2); t += stride) {
    int n = t >> 6;  // HID/2 == 64
    int c2 = t & 63;
    float2 v = ne2[x_idx[n] * 64 + c2];
    xb2[t] = (unsigned)f2bf(v.x) | ((unsigned)f2bf(v.y) << 16);
  }
  for (int e = i; e < NEDGES; e += stride) {
    int d = eidx[NEDGES + e];
    int pos = atomicAdd(&cnt[d], 1);
    if (pos < CAP) eout[((size_t)d << 6) + pos] = eidx[e] | (eattr[e] << 16);
  }
  for (int idx = i; idx < 65536; idx += stride) {
    int j = idx & 7;
    int l = (idx >> 3) & 63;
    int q = (idx >> 9) & 3;
    int t = (idx >> 11) & 7;
    int m = idx >> 14;
    int k = ((l >> 4) << 3) + j + (q << 5);
    int n = (t << 4) + (l & 15);
    int layer = m >> 1;
    const float* W = (m & 1) ? W2 : W1;
    float w = W[(size_t)layer * HID * HID + k * HID + n];
    unsigned short h = f2bf(w);
    Wpk[idx] = h;
    Wpk[idx + 65536] = f2bf(w - bf2f(h));
  }
}

// ===========================================================================
// affine: feats = bf16(scl_c * feats + sh_c)  (pre-applies BN of previous
// layer so the gather needs no per-channel affine registers)
// ===========================================================================
__global__ __launch_bounds__(256) void affine_kernel(
    unsigned int* __restrict__ feats, const float* __restrict__ stats,
    const float* __restrict__ gam, const float* __restrict__ bet) {
  int i = blockIdx.x * 256 + threadIdx.x;
  int stride = gridDim.x * 256;
  for (int t = i; t < NNODES * (HID / 2); t += stride) {
    int c0 = (t & 63) * 2;
    int c1 = c0 + 1;
    float mu0 = stats[c0] * (1.0f / NNODES);
    float va0 = stats[HID + c0] * (1.0f / NNODES) - mu0 * mu0;
    float s0 = gam[c0] * rsqrtf(va0 + BN_EPS);
    float sh0 = bet[c0] - mu0 * s0;
    float mu1 = stats[c1] * (1.0f / NNODES);
    float va1 = stats[HID + c1] * (1.0f / NNODES) - mu1 * mu1;
    float s1 = gam[c1] * rsqrtf(va1 + BN_EPS);
    float sh1 = bet[c1] - mu1 * s1;
    unsigned v = feats[t];
    float x0 = fmaf(bf2f((unsigned short)(v & 0xFFFF)), s0, sh0);
    float x1 = fmaf(bf2f((unsigned short)(v >> 16)), s1, sh1);
    feats[t] = (unsigned)f2bf(x0) | ((unsigned)f2bf(x1) << 16);
  }
}

// ===========================================================================
// Fused GINE layer [round-10 gather/GEMM] + persistent-block work stealing.
// No input affine (pre-applied by affine_kernel) -> minimal loop liveness,
// no spill at the 64-VGPR/8-wave budget.
// Grid = 1024 blocks (4/CU, 32 waves/CU); blocks pull NT=32 node tiles from
// a global counter. Gather: wave w owns 4 nodes; lanes = 16 ch-octets x 4
// edge slots (16B/lane bf16 rows). GEMM: mfma 16x16x32_bf16, bf16x3 split.
// ===========================================================================
#define NT 32
#define LDAF 132  // 128+4 floats: float4-aligned rows
#define NTILES ((NNODES + NT - 1) / NT)  // 1563
#define GRID_GINE 1024

__global__ __launch_bounds__(512, 8) void gine_mlp_kernel(
    const unsigned short* __restrict__ in_bf,
    const int* __restrict__ cnt, const int* __restrict__ eout,
    const float* __restrict__ edge_emb,
    const short8* __restrict__ Wh, const short8* __restrict__ Wl,
    const float* __restrict__ b1, const float* __restrict__ b2,
    unsigned short* __restrict__ out_bf, float* __restrict__ stats,
    const int* __restrict__ batch, float* __restrict__ gpool,
    int* __restrict__ tile_ctr) {
  __shared__ __align__(16) float hA[NT * LDAF];  // h0 -> h1 -> h2 (reused)
  __shared__ __align__(16) float eeL[4 * HID];   // edge_emb
  __shared__ int tile_s;

  const int tid = threadIdx.x;
  const int lane = tid & 63;
  const int wave = tid >> 6;   // 0..7

  if (tid < 4 * HID) eeL[tid] = edge_emb[tid];

  const int c8 = lane & 15;
  const int grp = lane >> 4;
  const int col = lane & 15;
  const int quad = lane >> 4;
  const int rbase = quad * 4;
  const int ch0 = wave * 16 + col;  // this wave's 16-channel tile
  const int aoff = quad * 8;
  const float bb1 = b1[ch0];
  const float bb2 = b2[ch0];

  for (;;) {
    if (tid == 0) tile_s = atomicAdd(tile_ctr, 1);
    __syncthreads();  // publishes tile_s; also: prev epilogue hA reads done
    const int tile = tile_s;
    if (tile >= NTILES) break;
    const int base = tile * NT;

    // ---- phase 1: gather: h0 = x + sum relu(x_src + ee[attr]) ----
    {
      const short8* in8 = (const short8*)in_bf;  // row = 16 short8s
      int node0 = base + wave * 4;
      int degs[4];
      #pragma unroll
      for (int i = 0; i < 4; i++) {
        int nd = node0 + i;
        degs[i] = (nd < NNODES) ? min(cnt[nd], CAP) : 0;
      }
      for (int i = 0; i < 4; i++) {
        int node = node0 + i;
        int nrow = wave * 4 + i;
        float acc[8];
        #pragma unroll
        for (int j = 0; j < 8; j++) acc[j] = 0.0f;
        if (node < NNODES) {
          int deg = degs[i];
          const int* ep = eout + ((size_t)node << 6);
          if (grp == 0) {
            short8 s = in8[node * 16 + c8];
            #pragma unroll
            for (int j = 0; j < 8; j++) acc[j] = bf2f((unsigned short)s[j]);
          }
          int e = 0;
          for (; e + 8 <= deg; e += 8) {  // 8 edges: 2 per slot
            int pA = ep[e + grp];
            int pB = ep[e + 4 + grp];
            short8 xA = in8[(pA & 0xFFFF) * 16 + c8];
            short8 xB = in8[(pB & 0xFFFF) * 16 + c8];
            const float4* sA = (const float4*)&eeL[((pA >> 16) << 7) + c8 * 8];
            const float4* sB = (const float4*)&eeL[((pB >> 16) << 7) + c8 * 8];
            float4 sA0 = sA[0], sA1 = sA[1], sB0 = sB[0], sB1 = sB[1];
            #pragma unroll
            for (int j = 0; j < 8; j++) {
              float seA = (j < 4) ? ((const float*)&sA0)[j] : ((const float*)&sA1)[j - 4];
              float seB = (j < 4) ? ((const float*)&sB0)[j] : ((const float*)&sB1)[j - 4];
              acc[j] += fmaxf(bf2f((unsigned short)xA[j]) + seA, 0.0f) +
                        fmaxf(bf2f((unsigned short)xB[j]) + seB, 0.0f);
            }
          }
          if (e + 4 <= deg) {
            int pA = ep[e + grp];
            short8 xA = in8[(pA & 0xFFFF) * 16 + c8];
            const float4* sA = (const float4*)&eeL[((pA >> 16) << 7) + c8 * 8];
            float4 sA0 = sA[0], sA1 = sA[1];
            #pragma unroll
            for (int j = 0; j < 8; j++) {
              float seA = (j < 4) ? ((const float*)&sA0)[j] : ((const float*)&sA1)[j - 4];
              acc[j] += fmaxf(bf2f((unsigned short)xA[j]) + seA, 0.0f);
            }
            e += 4;
          }
          int rem = deg - e;  // 0..3
          if (grp < rem) {
            int pA = ep[e + grp];
            short8 xA = in8[(pA & 0xFFFF) * 16 + c8];
            const float4* sA = (const float4*)&eeL[((pA >> 16) << 7) + c8 * 8];
            float4 sA0 = sA[0], sA1 = sA[1];
            #pragma unroll
            for (int j = 0; j < 8; j++) {
              float seA = (j < 4) ? ((const float*)&sA0)[j] : ((const float*)&sA1)[j - 4];
              acc[j] += fmaxf(bf2f((unsigned short)xA[j]) + seA, 0.0f);
            }
          }
        }
        #pragma unroll
        for (int j = 0; j < 8; j++) {
          acc[j] += __shfl_xor(acc[j], 16);
          acc[j] += __shfl_xor(acc[j], 32);
        }
        if (grp == 0) {
          float4 lo = make_float4(acc[0], acc[1], acc[2], acc[3]);
          float4 hi = make_float4(acc[4], acc[5], acc[6], acc[7]);
          *(float4*)&hA[nrow * LDAF + c8 * 8] = lo;
          *(float4*)&hA[nrow * LDAF + c8 * 8 + 4] = hi;
        }
      }
    }
    __syncthreads();

    // ---- phase 2: GEMM1 (hA @ W1 + b1, relu) -> back into hA ----
    {
      f32x4 a0 = {0.f, 0.f, 0.f, 0.f}, a1 = a0;
      #pragma unroll
      for (int q = 0; q < 4; q++) {
        int f0 = wave * 256 + q * 64 + lane;
        short8 b0h = Wh[f0], b0l = Wl[f0];
        short8 a0h, a0l, a1h, a1l;
        split8(&hA[col * LDAF + q * 32 + aoff], a0h, a0l);
        split8(&hA[(16 + col) * LDAF + q * 32 + aoff], a1h, a1l);
        a0 = __builtin_amdgcn_mfma_f32_16x16x32_bf16(a0h, b0h, a0, 0, 0, 0);
        a0 = __builtin_amdgcn_mfma_f32_16x16x32_bf16(a0l, b0h, a0, 0, 0, 0);
        a0 = __builtin_amdgcn_mfma_f32_16x16x32_bf16(a0h, b0l, a0, 0, 0, 0);
        a1 = __builtin_amdgcn_mfma_f32_16x16x32_bf16(a1h, b0h, a1, 0, 0, 0);
        a1 = __builtin_amdgcn_mfma_f32_16x16x32_bf16(a1l, b0h, a1, 0, 0, 0);
        a1 = __builtin_amdgcn_mfma_f32_16x16x32_bf16(a1h, b0l, a1, 0, 0, 0);
      }
      __syncthreads();  // all GEMM1 reads of hA complete
      #pragma unroll
      for (int r = 0; r < 4; r++) {
        hA[(rbase + r) * LDAF + ch0] = fmaxf(a0[r] + bb1, 0.0f);
        hA[(16 + rbase + r) * LDAF + ch0] = fmaxf(a1[r] + bb1, 0.0f);
      }
    }
    __syncthreads();

    // ---- phase 3: GEMM2 (h1 @ W2 + b2, relu) -> back into hA ----
    {
      f32x4 a0 = {0.f, 0.f, 0.f, 0.f}, a1 = a0;
      #pragma unroll
      for (int q = 0; q < 4; q++) {
        int f0 = 2048 + wave * 256 + q * 64 + lane;  // gemm2 frags
        short8 b0h = Wh[f0], b0l = Wl[f0];
        short8 a0h, a0l, a1h, a1l;
        split8(&hA[col * LDAF + q * 32 + aoff], a0h, a0l);
        split8(&hA[(16 + col) * LDAF + q * 32 + aoff], a1h, a1l);
        a0 = __builtin_amdgcn_mfma_f32_16x16x32_bf16(a0h, b0h, a0, 0, 0, 0);
        a0 = __builtin_amdgcn_mfma_f32_16x16x32_bf16(a0l, b0h, a0, 0, 0, 0);
        a0 = __builtin_amdgcn_mfma_f32_16x16x32_bf16(a0h, b0l, a0, 0, 0, 0);
        a1 = __builtin_amdgcn_mfma_f32_16x16x32_bf16(a1h, b0h, a1, 0, 0, 0);
        a1 = __builtin_amdgcn_mfma_f32_16x16x32_bf16(a1l, b0h, a1, 0, 0, 0);
        a1 = __builtin_amdgcn_mfma_f32_16x16x32_bf16(a1h, b0l, a1, 0, 0, 0);
      }
      __syncthreads();  // all GEMM2 reads complete
      #pragma unroll
      for (int r = 0; r < 4; r++) {
        hA[(rbase + r) * LDAF + ch0] = fmaxf(a0[r] + bb2, 0.0f);
        hA[(16 + rbase + r) * LDAF + ch0] = fmaxf(a1[r] + bb2, 0.0f);
      }
    }
    __syncthreads();

    // ---- phase 4: epilogue (h2 in hA); first 256 threads only ----
    if (tid < 256) {
      const int c = tid & 127;
      const int yy = tid >> 7;
      float lsum = 0.0f, lsq = 0.0f;
      if (out_bf) {
        #pragma unroll 4
        for (int i = 0; i < 16; i++) {
          int n = yy * 16 + i;
          int node = base + n;
          if (node < NNODES) {
            float v = hA[n * LDAF + c];
            out_bf[node * HID + c] = f2bf(v);
            lsum += v;
            lsq += v * v;
          }
        }
      } else {
        int curg = -1;
        float pacc = 0.0f;
        for (int i = 0; i < 16; i++) {
          int n = yy * 16 + i;
          int node = base + n;
          if (node < NNODES) {
            float v = hA[n * LDAF + c];
            lsum += v;
            lsq += v * v;
            int bg = batch[node];
            if (bg != curg) {
              if (curg >= 0) unsafeAtomicAdd(&gpool[curg * HID + c], pacc);
              curg = bg;
              pacc = 0.0f;
            }
            pacc += v;
          }
        }
        if (curg >= 0) unsafeAtomicAdd(&gpool[curg * HID + c], pacc);
      }
      unsafeAtomicAdd(&stats[c], lsum);
      unsafeAtomicAdd(&stats[HID + c], lsq);
    }
    // loop-top barrier protects hA against next tile's gather
  }
}

// ---------------------------------------------------------------------------
// out[g,c] = scl_c * gpool[g,c] + cnt_g * sh_c  (BN affine commutes with pool)
__device__ __forceinline__ int lbound(const int* __restrict__ arr, int n,
                                      int key) {
  int lo = 0, hi = n;
  while (lo < hi) {
    int mid = (lo + hi) >> 1;
    if (arr[mid] < key) lo = mid + 1; else hi = mid;
  }
  return lo;
}

__global__ __launch_bounds__(128) void finish_kernel(
    const float* __restrict__ gpool, const float* __restrict__ stats,
    const float* __restrict__ gam, const float* __restrict__ bet,
    const int* __restrict__ batch, float* __restrict__ out) {
  __shared__ int cnt_s;
  int g = blockIdx.x, c = threadIdx.x;
  if (c == 0)
    cnt_s = lbound(batch, NNODES, g + 1) - lbound(batch, NNODES, g);
  __syncthreads();
  float mu = stats[c] * (1.0f / NNODES);
  float var = stats[HID + c] * (1.0f / NNODES) - mu * mu;
  float scl = gam[c] * rsqrtf(var + BN_EPS);
  float sh = bet[c] - mu * scl;
  out[g * HID + c] = fmaf(gpool[g * HID + c], scl, (float)cnt_s * sh);
}

// ---------------------------------------------------------------------------
extern "C" void kernel_launch(void* const* d_in, const int* in_sizes, int n_in,
                              void* d_out, int out_size, void* d_ws, size_t ws_size,
                              hipStream_t stream) {
  const int* x_idx = (const int*)d_in[0];
  const int* eidx = (const int*)d_in[1];   // [2, E]: src row then dst row
  const int* eattr = (const int*)d_in[2];
  const int* batch = (const int*)d_in[3];
  const float* node_emb = (const float*)d_in[4];
  const float* edge_emb = (const float*)d_in[5];
  const float* W1 = (const float*)d_in[6];
  const float* b1 = (const float*)d_in[7];
  const float* W2 = (const float*)d_in[8];
  const float* b2 = (const float*)d_in[9];
  const float* bn_g = (const float*)d_in[10];
  const float* bn_b = (const float*)d_in[11];
  float* out = (float*)d_out;

  const size_t nfeat = (size_t)NNODES * HID;
  unsigned short* xbf = (unsigned short*)d_ws;  // [N,H] bf16
  unsigned short* h2bf = xbf + nfeat;           // [N,H] bf16
  float* stats0 = (float*)(h2bf + nfeat);       // [2,H]
  float* stats1 = stats0 + 2 * HID;             // [2,H]
  float* gpool = stats1 + 2 * HID;              // [G,H]
  int* ctrs = (int*)(gpool + NGRAPHS * HID);    // [2] tile counters
  int* cnt = ctrs + 2;                          // [N]  (zeroed with stats)
  int* eout = cnt + NNODES;                     // [N*CAP]
  unsigned short* Wpk = (unsigned short*)(eout + (size_t)NNODES * CAP);
  size_t needed = (size_t)((char*)(Wpk + 131072) - (char*)d_ws);
  if (ws_size < needed) return;  // fails validation loudly, doesn't corrupt

  // zero stats0, stats1, gpool, ctrs, cnt in one shot (contiguous)
  hipMemsetAsync(stats0, 0,
                 (4 * HID + NGRAPHS * HID + 2 + NNODES) * sizeof(int), stream);

  prep_kernel<<<1024, 256, 0, stream>>>(x_idx, node_emb, (unsigned int*)xbf,
                                        eidx, eattr, cnt, eout, W1, W2, Wpk);

  const short8* Wfh = (const short8*)Wpk;  // 8192 frags (hi)
  const short8* Wfl = Wfh + 8192;          // 8192 frags (lo)
  // layer 0: in = xbf, out -> h2bf (raw) + stats0
  gine_mlp_kernel<<<GRID_GINE, 512, 0, stream>>>(
      xbf, cnt, eout, edge_emb, Wfh + 0 * 2048, Wfl + 0 * 2048, b1, b2,
      h2bf, stats0, nullptr, nullptr, ctrs + 0);
  // pre-apply BN(layer0) affine to h2bf
  affine_kernel<<<2048, 256, 0, stream>>>((unsigned int*)h2bf, stats0, bn_g,
                                          bn_b);
  // layer 1: in = h2bf (already affine-applied), out -> gpool + stats1
  gine_mlp_kernel<<<GRID_GINE, 512, 0, stream>>>(
      h2bf, cnt, eout, edge_emb, Wfh + 2 * 2048, Wfl + 2 * 2048, b1 + HID,
      b2 + HID, nullptr, stats1, batch, gpool, ctrs + 1);
  // final: out = scl*gpool + cnt*sh
  finish_kernel<<<NGRAPHS, 128, 0, stream>>>(gpool, stats1, bn_g + HID,
                                             bn_b + HID, batch, out);
}

// Round 14
// 414.075 us; speedup vs baseline: 1.1908x; 1.0054x over previous
//
#include <hip/hip_runtime.h>
#include <hip/hip_bf16.h>

#define HID 128
#define NNODES 50000
#define NEDGES 800000
#define NGRAPHS 64
#define BN_EPS 1e-5f
#define CAP 64  // bucket capacity; deg ~ Poisson(16), P(deg>63) ~ 1e-21

typedef __attribute__((ext_vector_type(8))) short short8;   // 8 bf16 (4 VGPRs)
typedef __attribute__((ext_vector_type(4))) float f32x4;    // MFMA acc

static __device__ __forceinline__ unsigned short f2bf(float v) {
  __hip_bfloat16 b = __float2bfloat16(v);  // round-to-nearest
  return *reinterpret_cast<unsigned short*>(&b);
}
static __device__ __forceinline__ float bf2f(unsigned short u) {
  return __uint_as_float(((unsigned)u) << 16);
}

// split fp32 -> hi+lo bf16 pair (bf16x3 scheme), 8 contiguous LDS floats
static __device__ __forceinline__ void split8(const float* __restrict__ p,
                                              short8& hi, short8& lo) {
  #pragma unroll
  for (int j = 0; j < 8; j++) {
    float v = p[j];
    unsigned short h = f2bf(v);
    hi[j] = (short)h;
    lo[j] = (short)f2bf(v - bf2f(h));
  }
}

// ===========================================================================
// prep (single kernel): xbf = bf16(node_emb[x_idx]) + bucket-CSR build +
// weight pack (MFMA B-frag layout, hi/lo split).  [round-10 proven]
// ===========================================================================
__global__ __launch_bounds__(256) void prep_kernel(
    const int* __restrict__ x_idx, const float* __restrict__ node_emb,
    unsigned int* __restrict__ xb2, const int* __restrict__ eidx,
    const int* __restrict__ eattr, int* __restrict__ cnt,
    int* __restrict__ eout, const float* __restrict__ W1,
    const float* __restrict__ W2, unsigned short* __restrict__ Wpk) {
  int i = blockIdx.x * 256 + threadIdx.x;
  int stride = gridDim.x * 256;
  const float2* ne2 = (const float2*)node_emb;
  for (int t = i; t < NNODES * (HID / 2); t += stride) {
    int n = t >> 6;  // HID/2 == 64
    int c2 = t & 63;
    float2 v = ne2[x_idx[n] * 64 + c2];
    xb2[t] = (unsigned)f2bf(v.x) | ((unsigned)f2bf(v.y) << 16);
  }
  for (int e = i; e < NEDGES; e += stride) {
    int d = eidx[NEDGES + e];
    int pos = atomicAdd(&cnt[d], 1);
    if (pos < CAP) eout[((size_t)d << 6) + pos] = eidx[e] | (eattr[e] << 16);
  }
  for (int idx = i; idx < 65536; idx += stride) {
    int j = idx & 7;
    int l = (idx >> 3) & 63;
    int q = (idx >> 9) & 3;
    int t = (idx >> 11) & 7;
    int m = idx >> 14;
    int k = ((l >> 4) << 3) + j + (q << 5);
    int n = (t << 4) + (l & 15);
    int layer = m >> 1;
    const float* W = (m & 1) ? W2 : W1;
    float w = W[(size_t)layer * HID * HID + k * HID + n];
    unsigned short h = f2bf(w);
    Wpk[idx] = h;
    Wpk[idx + 65536] = f2bf(w - bf2f(h));
  }
}

// ===========================================================================
// affine: feats = bf16(scl_c * feats + sh_c)  (pre-applies BN of previous
// layer so the gather needs no per-channel affine registers)
// ===========================================================================
__global__ __launch_bounds__(256) void affine_kernel(
    unsigned int* __restrict__ feats, const float* __restrict__ stats,
    const float* __restrict__ gam, const float* __restrict__ bet) {
  int i = blockIdx.x * 256 + threadIdx.x;
  int stride = gridDim.x * 256;
  for (int t = i; t < NNODES * (HID / 2); t += stride) {
    int c0 = (t & 63) * 2;
    int c1 = c0 + 1;
    float mu0 = stats[c0] * (1.0f / NNODES);
    float va0 = stats[HID + c0] * (1.0f / NNODES) - mu0 * mu0;
    float s0 = gam[c0] * rsqrtf(va0 + BN_EPS);
    float sh0 = bet[c0] - mu0 * s0;
    float mu1 = stats[c1] * (1.0f / NNODES);
    float va1 = stats[HID + c1] * (1.0f / NNODES) - mu1 * mu1;
    float s1 = gam[c1] * rsqrtf(va1 + BN_EPS);
    float sh1 = bet[c1] - mu1 * s1;
    unsigned v = feats[t];
    float x0 = fmaf(bf2f((unsigned short)(v & 0xFFFF)), s0, sh0);
    float x1 = fmaf(bf2f((unsigned short)(v >> 16)), s1, sh1);
    feats[t] = (unsigned)f2bf(x0) | ((unsigned)f2bf(x1) << 16);
  }
}

// ===========================================================================
// Fused GINE layer [round-10 gather/GEMM] + persistent-block work stealing.
// asm memory clobber at loop top defeats LICM of the weight-fragment loads
// (hoisting them pins 64 VGPRs -> scratch spill at the (512,8) budget; the
// reloads are L2-hot and cheap).
// Grid = 1024 blocks (4/CU, 32 waves/CU); blocks pull NT=32 node tiles from
// a global counter. Gather: wave w owns 4 nodes; lanes = 16 ch-octets x 4
// edge slots (16B/lane bf16 rows). GEMM: mfma 16x16x32_bf16, bf16x3 split.
// ===========================================================================
#define NT 32
#define LDAF 132  // 128+4 floats: float4-aligned rows
#define NTILES ((NNODES + NT - 1) / NT)  // 1563
#define GRID_GINE 1024

__global__ __launch_bounds__(512, 8) void gine_mlp_kernel(
    const unsigned short* __restrict__ in_bf,
    const int* __restrict__ cnt, const int* __restrict__ eout,
    const float* __restrict__ edge_emb,
    const short8* __restrict__ Wh, const short8* __restrict__ Wl,
    const float* __restrict__ b1, const float* __restrict__ b2,
    unsigned short* __restrict__ out_bf, float* __restrict__ stats,
    const int* __restrict__ batch, float* __restrict__ gpool,
    int* __restrict__ tile_ctr) {
  __shared__ __align__(16) float hA[NT * LDAF];  // h0 -> h1 -> h2 (reused)
  __shared__ __align__(16) float eeL[4 * HID];   // edge_emb
  __shared__ int tile_s;

  const int tid = threadIdx.x;
  const int lane = tid & 63;
  const int wave = tid >> 6;   // 0..7

  if (tid < 4 * HID) eeL[tid] = edge_emb[tid];

  const int c8 = lane & 15;
  const int grp = lane >> 4;
  const int col = lane & 15;
  const int quad = lane >> 4;
  const int rbase = quad * 4;
  const int ch0 = wave * 16 + col;  // this wave's 16-channel tile
  const int aoff = quad * 8;
  const float bb1 = b1[ch0];
  const float bb2 = b2[ch0];

  for (;;) {
    if (tid == 0) tile_s = atomicAdd(tile_ctr, 1);
    __syncthreads();  // publishes tile_s; also: prev epilogue hA reads done
    const int tile = tile_s;
    if (tile >= NTILES) break;
    const int base = tile * NT;
    // Defeat LICM: without this, the loop-invariant Wh/Wl fragment loads are
    // hoisted into ~64 VGPRs and everything else spills to scratch (round-12/
    // 13 counters: WRITE_SIZE 153/80 MB of spill traffic).
    asm volatile("" ::: "memory");

    // ---- phase 1: gather: h0 = x + sum relu(x_src + ee[attr]) ----
    {
      const short8* in8 = (const short8*)in_bf;  // row = 16 short8s
      int node0 = base + wave * 4;
      int degs[4];
      #pragma unroll
      for (int i = 0; i < 4; i++) {
        int nd = node0 + i;
        degs[i] = (nd < NNODES) ? min(cnt[nd], CAP) : 0;
      }
      for (int i = 0; i < 4; i++) {
        int node = node0 + i;
        int nrow = wave * 4 + i;
        float acc[8];
        #pragma unroll
        for (int j = 0; j < 8; j++) acc[j] = 0.0f;
        if (node < NNODES) {
          int deg = degs[i];
          const int* ep = eout + ((size_t)node << 6);
          if (grp == 0) {
            short8 s = in8[node * 16 + c8];
            #pragma unroll
            for (int j = 0; j < 8; j++) acc[j] = bf2f((unsigned short)s[j]);
          }
          int e = 0;
          for (; e + 8 <= deg; e += 8) {  // 8 edges: 2 per slot
            int pA = ep[e + grp];
            int pB = ep[e + 4 + grp];
            short8 xA = in8[(pA & 0xFFFF) * 16 + c8];
            short8 xB = in8[(pB & 0xFFFF) * 16 + c8];
            const float4* sA = (const float4*)&eeL[((pA >> 16) << 7) + c8 * 8];
            const float4* sB = (const float4*)&eeL[((pB >> 16) << 7) + c8 * 8];
            float4 sA0 = sA[0], sA1 = sA[1], sB0 = sB[0], sB1 = sB[1];
            #pragma unroll
            for (int j = 0; j < 8; j++) {
              float seA = (j < 4) ? ((const float*)&sA0)[j] : ((const float*)&sA1)[j - 4];
              float seB = (j < 4) ? ((const float*)&sB0)[j] : ((const float*)&sB1)[j - 4];
              acc[j] += fmaxf(bf2f((unsigned short)xA[j]) + seA, 0.0f) +
                        fmaxf(bf2f((unsigned short)xB[j]) + seB, 0.0f);
            }
          }
          if (e + 4 <= deg) {
            int pA = ep[e + grp];
            short8 xA = in8[(pA & 0xFFFF) * 16 + c8];
            const float4* sA = (const float4*)&eeL[((pA >> 16) << 7) + c8 * 8];
            float4 sA0 = sA[0], sA1 = sA[1];
            #pragma unroll
            for (int j = 0; j < 8; j++) {
              float seA = (j < 4) ? ((const float*)&sA0)[j] : ((const float*)&sA1)[j - 4];
              acc[j] += fmaxf(bf2f((unsigned short)xA[j]) + seA, 0.0f);
            }
            e += 4;
          }
          int rem = deg - e;  // 0..3
          if (grp < rem) {
            int pA = ep[e + grp];
            short8 xA = in8[(pA & 0xFFFF) * 16 + c8];
            const float4* sA = (const float4*)&eeL[((pA >> 16) << 7) + c8 * 8];
            float4 sA0 = sA[0], sA1 = sA[1];
            #pragma unroll
            for (int j = 0; j < 8; j++) {
              float seA = (j < 4) ? ((const float*)&sA0)[j] : ((const float*)&sA1)[j - 4];
              acc[j] += fmaxf(bf2f((unsigned short)xA[j]) + seA, 0.0f);
            }
          }
        }
        #pragma unroll
        for (int j = 0; j < 8; j++) {
          acc[j] += __shfl_xor(acc[j], 16);
          acc[j] += __shfl_xor(acc[j], 32);
        }
        if (grp == 0) {
          float4 lo = make_float4(acc[0], acc[1], acc[2], acc[3]);
          float4 hi = make_float4(acc[4], acc[5], acc[6], acc[7]);
          *(float4*)&hA[nrow * LDAF + c8 * 8] = lo;
          *(float4*)&hA[nrow * LDAF + c8 * 8 + 4] = hi;
        }
      }
    }
    __syncthreads();

    // ---- phase 2: GEMM1 (hA @ W1 + b1, relu) -> back into hA ----
    {
      f32x4 a0 = {0.f, 0.f, 0.f, 0.f}, a1 = a0;
      #pragma unroll
      for (int q = 0; q < 4; q++) {
        int f0 = wave * 256 + q * 64 + lane;
        short8 b0h = Wh[f0], b0l = Wl[f0];
        short8 a0h, a0l, a1h, a1l;
        split8(&hA[col * LDAF + q * 32 + aoff], a0h, a0l);
        split8(&hA[(16 + col) * LDAF + q * 32 + aoff], a1h, a1l);
        a0 = __builtin_amdgcn_mfma_f32_16x16x32_bf16(a0h, b0h, a0, 0, 0, 0);
        a0 = __builtin_amdgcn_mfma_f32_16x16x32_bf16(a0l, b0h, a0, 0, 0, 0);
        a0 = __builtin_amdgcn_mfma_f32_16x16x32_bf16(a0h, b0l, a0, 0, 0, 0);
        a1 = __builtin_amdgcn_mfma_f32_16x16x32_bf16(a1h, b0h, a1, 0, 0, 0);
        a1 = __builtin_amdgcn_mfma_f32_16x16x32_bf16(a1l, b0h, a1, 0, 0, 0);
        a1 = __builtin_amdgcn_mfma_f32_16x16x32_bf16(a1h, b0l, a1, 0, 0, 0);
      }
      __syncthreads();  // all GEMM1 reads of hA complete
      #pragma unroll
      for (int r = 0; r < 4; r++) {
        hA[(rbase + r) * LDAF + ch0] = fmaxf(a0[r] + bb1, 0.0f);
        hA[(16 + rbase + r) * LDAF + ch0] = fmaxf(a1[r] + bb1, 0.0f);
      }
    }
    __syncthreads();

    // ---- phase 3: GEMM2 (h1 @ W2 + b2, relu) -> back into hA ----
    {
      f32x4 a0 = {0.f, 0.f, 0.f, 0.f}, a1 = a0;
      #pragma unroll
      for (int q = 0; q < 4; q++) {
        int f0 = 2048 + wave * 256 + q * 64 + lane;  // gemm2 frags
        short8 b0h = Wh[f0], b0l = Wl[f0];
        short8 a0h, a0l, a1h, a1l;
        split8(&hA[col * LDAF + q * 32 + aoff], a0h, a0l);
        split8(&hA[(16 + col) * LDAF + q * 32 + aoff], a1h, a1l);
        a0 = __builtin_amdgcn_mfma_f32_16x16x32_bf16(a0h, b0h, a0, 0, 0, 0);
        a0 = __builtin_amdgcn_mfma_f32_16x16x32_bf16(a0l, b0h, a0, 0, 0, 0);
        a0 = __builtin_amdgcn_mfma_f32_16x16x32_bf16(a0h, b0l, a0, 0, 0, 0);
        a1 = __builtin_amdgcn_mfma_f32_16x16x32_bf16(a1h, b0h, a1, 0, 0, 0);
        a1 = __builtin_amdgcn_mfma_f32_16x16x32_bf16(a1l, b0h, a1, 0, 0, 0);
        a1 = __builtin_amdgcn_mfma_f32_16x16x32_bf16(a1h, b0l, a1, 0, 0, 0);
      }
      __syncthreads();  // all GEMM2 reads complete
      #pragma unroll
      for (int r = 0; r < 4; r++) {
        hA[(rbase + r) * LDAF + ch0] = fmaxf(a0[r] + bb2, 0.0f);
        hA[(16 + rbase + r) * LDAF + ch0] = fmaxf(a1[r] + bb2, 0.0f);
      }
    }
    __syncthreads();

    // ---- phase 4: epilogue (h2 in hA); first 256 threads only ----
    if (tid < 256) {
      const int c = tid & 127;
      const int yy = tid >> 7;
      float lsum = 0.0f, lsq = 0.0f;
      if (out_bf) {
        #pragma unroll 4
        for (int i = 0; i < 16; i++) {
          int n = yy * 16 + i;
          int node = base + n;
          if (node < NNODES) {
            float v = hA[n * LDAF + c];
            out_bf[node * HID + c] = f2bf(v);
            lsum += v;
            lsq += v * v;
          }
        }
      } else {
        int curg = -1;
        float pacc = 0.0f;
        for (int i = 0; i < 16; i++) {
          int n = yy * 16 + i;
          int node = base + n;
          if (node < NNODES) {
            float v = hA[n * LDAF + c];
            lsum += v;
            lsq += v * v;
            int bg = batch[node];
            if (bg != curg) {
              if (curg >= 0) unsafeAtomicAdd(&gpool[curg * HID + c], pacc);
              curg = bg;
              pacc = 0.0f;
            }
            pacc += v;
          }
        }
        if (curg >= 0) unsafeAtomicAdd(&gpool[curg * HID + c], pacc);
      }
      unsafeAtomicAdd(&stats[c], lsum);
      unsafeAtomicAdd(&stats[HID + c], lsq);
    }
    // loop-top barrier protects hA against next tile's gather
  }
}

// ---------------------------------------------------------------------------
// out[g,c] = scl_c * gpool[g,c] + cnt_g * sh_c  (BN affine commutes with pool)
__device__ __forceinline__ int lbound(const int* __restrict__ arr, int n,
                                      int key) {
  int lo = 0, hi = n;
  while (lo < hi) {
    int mid = (lo + hi) >> 1;
    if (arr[mid] < key) lo = mid + 1; else hi = mid;
  }
  return lo;
}

__global__ __launch_bounds__(128) void finish_kernel(
    const float* __restrict__ gpool, const float* __restrict__ stats,
    const float* __restrict__ gam, const float* __restrict__ bet,
    const int* __restrict__ batch, float* __restrict__ out) {
  __shared__ int cnt_s;
  int g = blockIdx.x, c = threadIdx.x;
  if (c == 0)
    cnt_s = lbound(batch, NNODES, g + 1) - lbound(batch, NNODES, g);
  __syncthreads();
  float mu = stats[c] * (1.0f / NNODES);
  float var = stats[HID + c] * (1.0f / NNODES) - mu * mu;
  float scl = gam[c] * rsqrtf(var + BN_EPS);
  float sh = bet[c] - mu * scl;
  out[g * HID + c] = fmaf(gpool[g * HID + c], scl, (float)cnt_s * sh);
}

// ---------------------------------------------------------------------------
extern "C" void kernel_launch(void* const* d_in, const int* in_sizes, int n_in,
                              void* d_out, int out_size, void* d_ws, size_t ws_size,
                              hipStream_t stream) {
  const int* x_idx = (const int*)d_in[0];
  const int* eidx = (const int*)d_in[1];   // [2, E]: src row then dst row
  const int* eattr = (const int*)d_in[2];
  const int* batch = (const int*)d_in[3];
  const float* node_emb = (const float*)d_in[4];
  const float* edge_emb = (const float*)d_in[5];
  const float* W1 = (const float*)d_in[6];
  const float* b1 = (const float*)d_in[7];
  const float* W2 = (const float*)d_in[8];
  const float* b2 = (const float*)d_in[9];
  const float* bn_g = (const float*)d_in[10];
  const float* bn_b = (const float*)d_in[11];
  float* out = (float*)d_out;

  const size_t nfeat = (size_t)NNODES * HID;
  unsigned short* xbf = (unsigned short*)d_ws;  // [N,H] bf16
  unsigned short* h2bf = xbf + nfeat;           // [N,H] bf16
  float* stats0 = (float*)(h2bf + nfeat);       // [2,H]
  float* stats1 = stats0 + 2 * HID;             // [2,H]
  float* gpool = stats1 + 2 * HID;              // [G,H]
  int* ctrs = (int*)(gpool + NGRAPHS * HID);    // [2] tile counters
  int* cnt = ctrs + 2;                          // [N]  (zeroed with stats)
  int* eout = cnt + NNODES;                     // [N*CAP]
  unsigned short* Wpk = (unsigned short*)(eout + (size_t)NNODES * CAP);
  size_t needed = (size_t)((char*)(Wpk + 131072) - (char*)d_ws);
  if (ws_size < needed) return;  // fails validation loudly, doesn't corrupt

  // zero stats0, stats1, gpool, ctrs, cnt in one shot (contiguous)
  hipMemsetAsync(stats0, 0,
                 (4 * HID + NGRAPHS * HID + 2 + NNODES) * sizeof(int), stream);

  prep_kernel<<<1024, 256, 0, stream>>>(x_idx, node_emb, (unsigned int*)xbf,
                                        eidx, eattr, cnt, eout, W1, W2, Wpk);

  const short8* Wfh = (const short8*)Wpk;  // 8192 frags (hi)
  const short8* Wfl = Wfh + 8192;          // 8192 frags (lo)
  // layer 0: in = xbf, out -> h2bf (raw) + stats0
  gine_mlp_kernel<<<GRID_GINE, 512, 0, stream>>>(
      xbf, cnt, eout, edge_emb, Wfh + 0 * 2048, Wfl + 0 * 2048, b1, b2,
      h2bf, stats0, nullptr, nullptr, ctrs + 0);
  // pre-apply BN(layer0) affine to h2bf
  affine_kernel<<<2048, 256, 0, stream>>>((unsigned int*)h2bf, stats0, bn_g,
                                          bn_b);
  // layer 1: in = h2bf (already affine-applied), out -> gpool + stats1
  gine_mlp_kernel<<<GRID_GINE, 512, 0, stream>>>(
      h2bf, cnt, eout, edge_emb, Wfh + 2 * 2048, Wfl + 2 * 2048, b1 + HID,
      b2 + HID, nullptr, stats1, batch, gpool, ctrs + 1);
  // final: out = scl*gpool + cnt*sh
  finish_kernel<<<NGRAPHS, 128, 0, stream>>>(gpool, stats1, bn_g + HID,
                                             bn_b + HID, batch, out);
}